// Round 5
// baseline (157.269 us; speedup 1.0000x reference)
//
#include <hip/hip_runtime.h>

// VQ codebook lookup via MFMA on MI355X (gfx950) — single fused kernel.
// x: [32,64,64,64] f32 -> N=131072 rows, DIM=64; embed: [64, 512] f32.
// fp32 exactly decomposed into 3 bf16 planes (8+8+8 mantissa bits, truncation);
// dot = 6 cross-products accumulated in fp32 MFMA -> ~1e-6 error (fp32-grade).
// Outputs (flat f32): quantize [N*64], diff [1], embed_ind [N].
//
// R5 = R4 with the launch-grid fix: 64 rows/wave * 4 waves = 256 rows/block
// -> grid must be NVEC/256 = 512 blocks (R4 launched NVEC/128 -> OOB crash).

#define DIM      64
#define NCODE    512
#define NVEC     (32 * 64 * 64)   // 131072
#define BLK      256
#define NCT      16               // col-tiles of 32 codes
#define TILE_DW  3072             // dwords per tile buffer (12 KB)

typedef unsigned int u32;
typedef __attribute__((ext_vector_type(8)))  short bf16x8;
typedef __attribute__((ext_vector_type(16))) float f32x16;

// Exact 3-plane bf16 split: v == hi + mid + lo (24 mantissa bits in 3x8).
__device__ __forceinline__ void split3(float v, u32& h, u32& m, u32& lo) {
    const u32 u = __float_as_uint(v);
    h = u >> 16;
    const float r1 = v - __uint_as_float(u & 0xFFFF0000u);
    const u32 u1 = __float_as_uint(r1);
    m = u1 >> 16;
    const float r2 = r1 - __uint_as_float(u1 & 0xFFFF0000u);
    lo = __float_as_uint(r2) >> 16;
}

// Split 8 staged embed values into 3 bf16-plane fragments and write to LDS.
// Layout identical to validated R3 bfrag: [plane][s][lane=c+32*kh][4 dwords].
__device__ __forceinline__ void stage_write(const float* v, u32* dst,
                                            int ss, int lb) {
    u32 wH[4], wM[4], wL[4];
    #pragma unroll
    for (int q = 0; q < 4; ++q) {
        u32 h0, m0, l0, h1, m1, l1;
        split3(v[2 * q],     h0, m0, l0);
        split3(v[2 * q + 1], h1, m1, l1);
        wH[q] = h0 | (h1 << 16);
        wM[q] = m0 | (m1 << 16);
        wL[q] = l0 | (l1 << 16);
    }
    *reinterpret_cast<uint4*>(dst + (0 * 4 + ss) * 256 + lb * 4) =
        make_uint4(wH[0], wH[1], wH[2], wH[3]);
    *reinterpret_cast<uint4*>(dst + (1 * 4 + ss) * 256 + lb * 4) =
        make_uint4(wM[0], wM[1], wM[2], wM[3]);
    *reinterpret_cast<uint4*>(dst + (2 * 4 + ss) * 256 + lb * 4) =
        make_uint4(wL[0], wL[1], wL[2], wL[3]);
}

__global__ __launch_bounds__(BLK, 2) void vq_fused(
        const float* __restrict__ x,
        const float* __restrict__ embed,
        float* __restrict__ out) {
    __shared__ __align__(16) u32 lbuf[2][TILE_DW];   // double-buffered tile (24 KB)
    __shared__ float lnorm[NCODE];
    __shared__ int sbk[4][64];
    __shared__ float red[4];

    const int tid = threadIdx.x;
    const int wid = tid >> 6, l = tid & 63;
    const int rl = l & 31, kh = l >> 5;
    const int n0 = (blockIdx.x * 4 + wid) * 64;   // wave's 64 rows (2 groups)

    // staging role: thread = (code-in-tile sc, k-half skh, k-step ss)
    const int sc  = tid & 31;
    const int skh = (tid >> 5) & 1;
    const int ss  = tid >> 6;
    const int srow = (16 * ss + 8 * skh) * NCODE + sc;   // embed offset for j=0
    const int slb  = sc + 32 * skh;

    // ---- prologue ----
    // issue tile-0 staging loads first (latency hides under norms + A-build)
    float ev[8];
    {
        const float* ep = embed + srow;   // tile 0: codes 0..31
        #pragma unroll
        for (int j = 0; j < 8; ++j) ev[j] = ep[j * NCODE];
    }
    // per-code squared norms, f64 accumulate (2 codes per thread, coalesced)
    {
        double ns0 = 0.0, ns1 = 0.0;
        #pragma unroll 8
        for (int d = 0; d < DIM; ++d) {
            const float a = embed[d * NCODE + tid];
            const float b = embed[d * NCODE + tid + 256];
            ns0 += (double)a * (double)a;
            ns1 += (double)b * (double)b;
        }
        lnorm[tid]       = (float)ns0;
        lnorm[tid + 256] = (float)ns1;
    }
    // A fragments: 2 row-groups x 32 rows x 64 dims, 3 planes x 4 k-steps
    bf16x8 afr[2][3][4];
    #pragma unroll
    for (int g = 0; g < 2; ++g) {
        const float* xp = x + (size_t)(n0 + g * 32 + rl) * DIM + kh * 8;
        #pragma unroll
        for (int s = 0; s < 4; ++s) {
            const float4 va = *reinterpret_cast<const float4*>(xp + 16 * s);
            const float4 vb = *reinterpret_cast<const float4*>(xp + 16 * s + 4);
            const float v[8] = {va.x, va.y, va.z, va.w, vb.x, vb.y, vb.z, vb.w};
            #pragma unroll
            for (int q = 0; q < 4; ++q) {
                u32 h0, m0, l0, h1, m1, l1;
                split3(v[2 * q],     h0, m0, l0);
                split3(v[2 * q + 1], h1, m1, l1);
                afr[g][0][s][2 * q] = (short)h0;  afr[g][0][s][2 * q + 1] = (short)h1;
                afr[g][1][s][2 * q] = (short)m0;  afr[g][1][s][2 * q + 1] = (short)m1;
                afr[g][2][s][2 * q] = (short)l0;  afr[g][2][s][2 * q + 1] = (short)l1;
            }
        }
    }
    // stage tile 0
    stage_write(ev, &lbuf[0][0], ss, slb);
    __syncthreads();

    float best[2][16];
    int bk[2][16];
    #pragma unroll
    for (int g = 0; g < 2; ++g)
        #pragma unroll
        for (int r = 0; r < 16; ++r) { best[g][r] = __builtin_inff(); bk[g][r] = 0; }

    // ---- main loop: ONE barrier per tile ----
    // iter ct: [issue loads ct+1] [compute from buf cur] [split+write buf cur^1]
    //          [__syncthreads]  -- writes to cur^1 only conflict with tile
    //          ct-1 reads, already behind ct-1's end barrier.
    int cur = 0;
    for (int ct = 0; ct < NCT; ++ct) {
        float ev2[8];
        if (ct + 1 < NCT) {
            const float* ep = embed + srow + (ct + 1) * 32;
            #pragma unroll
            for (int j = 0; j < 8; ++j) ev2[j] = ep[j * NCODE];
        }

        f32x16 acc0, acc1;
        #pragma unroll
        for (int r = 0; r < 16; ++r) { acc0[r] = 0.0f; acc1[r] = 0.0f; }

        const u32* lb0 = &lbuf[cur][0];
        const int l4 = l << 2;
        #pragma unroll
        for (int s = 0; s < 4; ++s) {
            const bf16x8 bh = *reinterpret_cast<const bf16x8*>(lb0 + (0 + s) * 256 + l4);
            const bf16x8 bm = *reinterpret_cast<const bf16x8*>(lb0 + (4 + s) * 256 + l4);
            const bf16x8 bl = *reinterpret_cast<const bf16x8*>(lb0 + (8 + s) * 256 + l4);
            acc0 = __builtin_amdgcn_mfma_f32_32x32x16_bf16(afr[0][0][s], bh, acc0, 0, 0, 0);
            acc1 = __builtin_amdgcn_mfma_f32_32x32x16_bf16(afr[1][0][s], bh, acc1, 0, 0, 0);
            acc0 = __builtin_amdgcn_mfma_f32_32x32x16_bf16(afr[0][0][s], bm, acc0, 0, 0, 0);
            acc1 = __builtin_amdgcn_mfma_f32_32x32x16_bf16(afr[1][0][s], bm, acc1, 0, 0, 0);
            acc0 = __builtin_amdgcn_mfma_f32_32x32x16_bf16(afr[0][1][s], bh, acc0, 0, 0, 0);
            acc1 = __builtin_amdgcn_mfma_f32_32x32x16_bf16(afr[1][1][s], bh, acc1, 0, 0, 0);
            acc0 = __builtin_amdgcn_mfma_f32_32x32x16_bf16(afr[0][1][s], bm, acc0, 0, 0, 0);
            acc1 = __builtin_amdgcn_mfma_f32_32x32x16_bf16(afr[1][1][s], bm, acc1, 0, 0, 0);
            acc0 = __builtin_amdgcn_mfma_f32_32x32x16_bf16(afr[0][0][s], bl, acc0, 0, 0, 0);
            acc1 = __builtin_amdgcn_mfma_f32_32x32x16_bf16(afr[1][0][s], bl, acc1, 0, 0, 0);
            acc0 = __builtin_amdgcn_mfma_f32_32x32x16_bf16(afr[0][2][s], bh, acc0, 0, 0, 0);
            acc1 = __builtin_amdgcn_mfma_f32_32x32x16_bf16(afr[1][2][s], bh, acc1, 0, 0, 0);
        }

        const int col = ct * 32 + rl;
        const float nrm = lnorm[col];
        #pragma unroll
        for (int r = 0; r < 16; ++r) {
            const float s0 = fmaf(-2.0f, acc0[r], nrm);
            if (s0 < best[0][r]) { best[0][r] = s0; bk[0][r] = col; }
            const float s1 = fmaf(-2.0f, acc1[r], nrm);
            if (s1 < best[1][r]) { best[1][r] = s1; bk[1][r] = col; }
        }

        if (ct + 1 < NCT) stage_write(ev2, &lbuf[cur ^ 1][0], ss, slb);
        __syncthreads();
        cur ^= 1;
    }

    // ---- cross-lane argmin over 32 cols (within each 32-lane half), np tie-break ----
    #pragma unroll
    for (int off = 1; off <= 16; off <<= 1) {
        #pragma unroll
        for (int g = 0; g < 2; ++g)
            #pragma unroll
            for (int r = 0; r < 16; ++r) {
                const float ob = __shfl_xor(best[g][r], off, 64);
                const int obk  = __shfl_xor(bk[g][r], off, 64);
                if (ob < best[g][r] || (ob == best[g][r] && obk < bk[g][r])) {
                    best[g][r] = ob; bk[g][r] = obk;
                }
            }
    }
    // C layout (m74/m101): row = g*32 + (r&3) + 8*(r>>2) + 4*kh, col = lane&31
    if (rl == 0) {
        #pragma unroll
        for (int g = 0; g < 2; ++g)
            #pragma unroll
            for (int r = 0; r < 16; ++r)
                sbk[wid][g * 32 + (r & 3) + 8 * (r >> 2) + 4 * kh] = bk[g][r];
    }
    // sbk[wid] written and read only by wave wid -> wave-ordered LDS, no barrier.

    // ---- epilogue: coalesced quantize write + diff + indices ----
    float dp = 0.0f;
    const int rsub = l >> 4;            // 0..3
    const int dcol = (l & 15) * 4;      // 0..60
    #pragma unroll
    for (int i = 0; i < 16; ++i) {
        const int row = i * 4 + rsub;   // 0..63
        const int k = sbk[wid][row];
        // gather winning code dims dcol..dcol+3 from L2-resident embed
        const float q0 = embed[(dcol + 0) * NCODE + k];
        const float q1 = embed[(dcol + 1) * NCODE + k];
        const float q2 = embed[(dcol + 2) * NCODE + k];
        const float q3 = embed[(dcol + 3) * NCODE + k];
        const float4 xv = *reinterpret_cast<const float4*>(
            x + (size_t)(n0 + row) * DIM + dcol);
        *reinterpret_cast<float4*>(out + (size_t)(n0 + row) * DIM + dcol) =
            make_float4(q0, q1, q2, q3);
        const float d0 = q0 - xv.x, d1 = q1 - xv.y, d2 = q2 - xv.z, d3 = q3 - xv.w;
        dp = fmaf(d0, d0, dp); dp = fmaf(d1, d1, dp);
        dp = fmaf(d2, d2, dp); dp = fmaf(d3, d3, dp);
    }
    out[(size_t)NVEC * DIM + 1 + n0 + l] = (float)sbk[wid][l];

    #pragma unroll
    for (int off = 32; off >= 1; off >>= 1) dp += __shfl_down(dp, off, 64);
    if (l == 0) red[wid] = dp;
    __syncthreads();
    if (tid == 0) {
        const float s = (red[0] + red[1]) + (red[2] + red[3]);
        atomicAdd(out + (size_t)NVEC * DIM, s * (1.0f / ((float)NVEC * (float)DIM)));
    }
}

extern "C" void kernel_launch(void* const* d_in, const int* in_sizes, int n_in,
                              void* d_out, int out_size, void* d_ws, size_t ws_size,
                              hipStream_t stream) {
    const float* x     = (const float*)d_in[0];
    const float* embed = (const float*)d_in[1];
    float* out = (float*)d_out;

    // zero the diff accumulator slot (d_out is poisoned 0xAA before each call)
    hipMemsetAsync((char*)d_out + (size_t)NVEC * DIM * sizeof(float), 0,
                   sizeof(float), stream);

    // 256 rows per block (4 waves x 64 rows) -> exactly NVEC/256 = 512 blocks
    vq_fused<<<NVEC / 256, BLK, 0, stream>>>(x, embed, out);
}

// Round 6
// 145.513 us; speedup vs baseline: 1.0808x; 1.0808x over previous
//
#include <hip/hip_runtime.h>

// VQ codebook lookup via MFMA on MI355X (gfx950).
// x: [32,64,64,64] f32 -> N=131072 rows, DIM=64; embed: [64, 512] f32.
// fp32 exactly decomposed into 3 bf16 planes (8+8+8 mantissa bits, truncation);
// dot = 6 cross-products accumulated in fp32 MFMA -> ~1e-6 error (fp32-grade).
// Outputs (flat f32): quantize [N*64], diff [1], embed_ind [N].
//
// R6: barrier-free main kernel. B-fragments (192 KB, prep-built in ws) are
// L2-resident; each wave loads them straight to VGPRs (12 dwordx4 per tile,
// coalesced) -- no LDS staging, no split3 in the hot loop, ZERO barriers in
// the main loop. R=1 (32 rows/wave), 1024 blocks, launch_bounds(256,3).
// MFMA order / bit-construction identical to the validated R3 kernel.

#define DIM      64
#define NCODE    512
#define NVEC     (32 * 64 * 64)   // 131072
#define WAVES    4
#define BLK      256
#define NCT      16               // col-tiles of 32 codes
#define CHUNK_DW 3072             // dwords per col-tile frag chunk (12 KB)

typedef unsigned int u32;
typedef __attribute__((ext_vector_type(8)))  short bf16x8;
typedef __attribute__((ext_vector_type(16))) float f32x16;

// Exact 3-plane bf16 split: v == hi + mid + lo (24 mantissa bits in 3x8).
__device__ __forceinline__ void split3(float v, u32& h, u32& m, u32& lo) {
    const u32 u = __float_as_uint(v);
    h = u >> 16;
    const float r1 = v - __uint_as_float(u & 0xFFFF0000u);
    const u32 u1 = __float_as_uint(r1);
    m = u1 >> 16;
    const float r2 = r1 - __uint_as_float(u1 & 0xFFFF0000u);
    lo = __float_as_uint(r2) >> 16;
}

// 16 blocks x 256 = 4096 threads: thread = (code c, 8-dim chunk g).
// Builds B-fragments (3 planes, MFMA frag layout), et transpose, f64 norms,
// and zeroes the diff output slot.  (Validated in R3.)
__global__ void vq_prep(const float* __restrict__ embed,
                        u32* __restrict__ bfrag,
                        float* __restrict__ et,
                        float* __restrict__ norms,
                        float* __restrict__ out) {
    const int gid = blockIdx.x * BLK + threadIdx.x;   // [0, 4096)
    const int c = gid >> 3, g = gid & 7;
    const int s = g >> 1, kh = g & 1;                 // dims 16s + 8kh + j

    float v[8];
    double ns = 0.0;
    #pragma unroll
    for (int j = 0; j < 8; ++j) {
        v[j] = embed[(16 * s + 8 * kh + j) * NCODE + c];
        ns += (double)v[j] * (double)v[j];
    }
    // reduce squared norm across the 8 threads sharing code c (same wave)
    ns += __shfl_xor(ns, 1, 64);
    ns += __shfl_xor(ns, 2, 64);
    ns += __shfl_xor(ns, 4, 64);
    if (g == 0) norms[c] = (float)ns;

    u32 wH[4], wM[4], wL[4];
    #pragma unroll
    for (int q = 0; q < 4; ++q) {
        u32 h0, m0, l0, h1, m1, l1;
        split3(v[2 * q],     h0, m0, l0);
        split3(v[2 * q + 1], h1, m1, l1);
        wH[q] = h0 | (h1 << 16);
        wM[q] = m0 | (m1 << 16);
        wL[q] = l0 | (l1 << 16);
    }
    const int ct = c >> 5, lb = (c & 31) + 32 * kh;
    u32* base = bfrag + ct * CHUNK_DW;
    *reinterpret_cast<uint4*>(base + (0 * 4 + s) * 256 + lb * 4) =
        make_uint4(wH[0], wH[1], wH[2], wH[3]);
    *reinterpret_cast<uint4*>(base + (1 * 4 + s) * 256 + lb * 4) =
        make_uint4(wM[0], wM[1], wM[2], wM[3]);
    *reinterpret_cast<uint4*>(base + (2 * 4 + s) * 256 + lb * 4) =
        make_uint4(wL[0], wL[1], wL[2], wL[3]);

    // et transpose: et[c][d] = embed[d][c] for this thread's 8 dims
    float* ep = et + c * DIM + 16 * s + 8 * kh;
    *reinterpret_cast<float4*>(ep)     = make_float4(v[0], v[1], v[2], v[3]);
    *reinterpret_cast<float4*>(ep + 4) = make_float4(v[4], v[5], v[6], v[7]);

    if (gid == 0) out[(size_t)NVEC * DIM] = 0.0f;   // diff accumulator slot
}

__global__ __launch_bounds__(BLK, 3) void vq_main(
        const float* __restrict__ x,
        const u32* __restrict__ bfrag,
        const float* __restrict__ et,
        const float* __restrict__ norms,
        float* __restrict__ out) {
    __shared__ int sbk[WAVES][32];
    __shared__ float red[WAVES];

    const int tid = threadIdx.x;
    const int wid = tid >> 6, l = tid & 63;
    const int rl = l & 31, kh = l >> 5;
    const int n0 = (blockIdx.x * WAVES + wid) * 32;   // wave's 32 rows

    // ---- A fragments: 32 rows x 64 dims, 3 planes x 4 k-steps, in VGPRs ----
    bf16x8 afr[3][4];
    {
        const float* xp = x + (size_t)(n0 + rl) * DIM + kh * 8;
        #pragma unroll
        for (int s = 0; s < 4; ++s) {
            const float4 va = *reinterpret_cast<const float4*>(xp + 16 * s);
            const float4 vb = *reinterpret_cast<const float4*>(xp + 16 * s + 4);
            const float v[8] = {va.x, va.y, va.z, va.w, vb.x, vb.y, vb.z, vb.w};
            #pragma unroll
            for (int q = 0; q < 4; ++q) {
                u32 h0, m0, l0, h1, m1, l1;
                split3(v[2 * q],     h0, m0, l0);
                split3(v[2 * q + 1], h1, m1, l1);
                afr[0][s][2 * q] = (short)h0;  afr[0][s][2 * q + 1] = (short)h1;
                afr[1][s][2 * q] = (short)m0;  afr[1][s][2 * q + 1] = (short)m1;
                afr[2][s][2 * q] = (short)l0;  afr[2][s][2 * q + 1] = (short)l1;
            }
        }
    }

    float best[16];
    int bk[16];
    #pragma unroll
    for (int r = 0; r < 16; ++r) { best[r] = __builtin_inff(); bk[r] = 0; }

    // ---- main loop: NO barriers, no LDS. B-frags straight from L2 to VGPRs ----
    const u32* fb = bfrag + (l << 2);   // lane base into frag layout
    for (int ct = 0; ct < NCT; ++ct) {
        const u32* tb = fb + ct * CHUNK_DW;
        // load s-major so the first MFMAs' operands land first
        bf16x8 b[3][4];
        #pragma unroll
        for (int s = 0; s < 4; ++s) {
            b[0][s] = *reinterpret_cast<const bf16x8*>(tb + (0 * 4 + s) * 256);
            b[1][s] = *reinterpret_cast<const bf16x8*>(tb + (1 * 4 + s) * 256);
            b[2][s] = *reinterpret_cast<const bf16x8*>(tb + (2 * 4 + s) * 256);
        }
        const float nrm = norms[ct * 32 + rl];

        f32x16 acc;
        #pragma unroll
        for (int r = 0; r < 16; ++r) acc[r] = 0.0f;

        // s-major, single chain -- bit-identical summation order to R3 (passed)
        #pragma unroll
        for (int s = 0; s < 4; ++s) {
            acc = __builtin_amdgcn_mfma_f32_32x32x16_bf16(afr[0][s], b[0][s], acc, 0, 0, 0);
            acc = __builtin_amdgcn_mfma_f32_32x32x16_bf16(afr[0][s], b[1][s], acc, 0, 0, 0);
            acc = __builtin_amdgcn_mfma_f32_32x32x16_bf16(afr[1][s], b[0][s], acc, 0, 0, 0);
            acc = __builtin_amdgcn_mfma_f32_32x32x16_bf16(afr[1][s], b[1][s], acc, 0, 0, 0);
            acc = __builtin_amdgcn_mfma_f32_32x32x16_bf16(afr[0][s], b[2][s], acc, 0, 0, 0);
            acc = __builtin_amdgcn_mfma_f32_32x32x16_bf16(afr[2][s], b[0][s], acc, 0, 0, 0);
        }

        const int col = ct * 32 + rl;
        #pragma unroll
        for (int r = 0; r < 16; ++r) {
            const float sc = fmaf(-2.0f, acc[r], nrm);   // ||x||^2 constant per row: dropped
            if (sc < best[r]) { best[r] = sc; bk[r] = col; }   // strict < => first index on ties
        }
    }

    // ---- cross-lane argmin over the 32 columns (lanes sharing kh), np tie-break ----
    #pragma unroll
    for (int off = 1; off <= 16; off <<= 1) {
        #pragma unroll
        for (int r = 0; r < 16; ++r) {
            const float ob = __shfl_xor(best[r], off, 64);
            const int obk  = __shfl_xor(bk[r], off, 64);
            if (ob < best[r] || (ob == best[r] && obk < bk[r])) { best[r] = ob; bk[r] = obk; }
        }
    }
    // C layout (m74/m101): row = (r&3) + 8*(r>>2) + 4*kh, col = lane&31
    if (rl == 0) {
        #pragma unroll
        for (int r = 0; r < 16; ++r) sbk[wid][(r & 3) + 8 * (r >> 2) + 4 * kh] = bk[r];
    }
    // sbk[wid] written and read only by wave wid -> wave-ordered LDS, no barrier.

    // ---- epilogue: coalesced quantize write + diff + indices ----
    float dp = 0.0f;
    const int rsub = l >> 4;            // 0..3
    const int dcol = (l & 15) * 4;      // 0..60
    #pragma unroll
    for (int i = 0; i < 8; ++i) {
        const int row = i * 4 + rsub;
        const int k = sbk[wid][row];
        const float4 q  = *reinterpret_cast<const float4*>(et + k * DIM + dcol);
        const float4 xv = *reinterpret_cast<const float4*>(x + (size_t)(n0 + row) * DIM + dcol);
        *reinterpret_cast<float4*>(out + (size_t)(n0 + row) * DIM + dcol) = q;
        const float d0 = q.x - xv.x, d1 = q.y - xv.y, d2 = q.z - xv.z, d3 = q.w - xv.w;
        dp = fmaf(d0, d0, dp); dp = fmaf(d1, d1, dp);
        dp = fmaf(d2, d2, dp); dp = fmaf(d3, d3, dp);
    }
    if (l < 32) out[(size_t)NVEC * DIM + 1 + n0 + l] = (float)sbk[wid][l];

    #pragma unroll
    for (int off = 32; off >= 1; off >>= 1) dp += __shfl_down(dp, off, 64);
    if (l == 0) red[wid] = dp;
    __syncthreads();
    if (tid == 0) {
        const float s = (red[0] + red[1]) + (red[2] + red[3]);
        atomicAdd(out + (size_t)NVEC * DIM, s * (1.0f / ((float)NVEC * (float)DIM)));
    }
}

extern "C" void kernel_launch(void* const* d_in, const int* in_sizes, int n_in,
                              void* d_out, int out_size, void* d_ws, size_t ws_size,
                              hipStream_t stream) {
    const float* x     = (const float*)d_in[0];
    const float* embed = (const float*)d_in[1];
    float* out = (float*)d_out;

    u32* bfrag   = (u32*)d_ws;                       // 16*3072 dwords = 192 KB
    float* et    = (float*)d_ws + NCT * CHUNK_DW;    // 512*64 f32 = 128 KB
    float* norms = et + (size_t)NCODE * DIM;         // 512 f32

    vq_prep<<<16, BLK, 0, stream>>>(embed, bfrag, et, norms, out);
    vq_main<<<NVEC / (WAVES * 32), BLK, 0, stream>>>(x, bfrag, et, norms, out);
}